// Round 5
// baseline (4679.193 us; speedup 1.0000x reference)
//
#include <hip/hip_runtime.h>
#include <hip/hip_bf16.h>

#define N_   128
#define L_   512
#define NB_  4
#define D_   1024
#define H_   16
#define DH_  64
#define IN_  1024
#define T_   512

#define KS_  8       // GEMM K-splits (Kc = 128)
#define NCV_ 32      // attention chunks per sample (16 rows each)

// ---------------------------------------------------------------- pos table + counter zero
__global__ __launch_bounds__(512) void pos_kernel(float* __restrict__ pos, int* __restrict__ cnt) {
  if (blockIdx.x == 0 && threadIdx.x < 256) cnt[threadIdx.x] = 0;
  int t = blockIdx.x;          // 0..511
  int j = threadIdx.x;         // 0..511
  float seq = (float)(T_ - 1 - t);
  float ex  = (float)(2 * j) * (1.0f / (float)D_);
  float inv = expf(-ex * 9.210340371976184f);   // 10000^(-2j/D)
  float si  = seq * inv;
  pos[(size_t)t * D_ + j]        = sinf(si);
  pos[(size_t)t * D_ + 512 + j]  = cosf(si);
}

// ---------------------------------------------------------------- LN + qk fold (device helper)
__device__ __forceinline__ void ln_qk_epilogue(int n, const float* v4, int tid,
                                               const float* __restrict__ lg,
                                               const float* __restrict__ lb,
                                               const float* __restrict__ Wq,
                                               const float* __restrict__ Wk,
                                               float* __restrict__ qkb,
                                               float* qln, float* Qp /*LDS 1024 each*/) {
  int c = tid * 4;
  float s = v4[0] + v4[1] + v4[2] + v4[3];
  float q = v4[0]*v4[0] + v4[1]*v4[1] + v4[2]*v4[2] + v4[3]*v4[3];
  __shared__ float sa[4], sb[4];
  #pragma unroll
  for (int o = 32; o; o >>= 1) { s += __shfl_xor(s, o, 64); q += __shfl_xor(q, o, 64); }
  if ((tid & 63) == 0) { sa[tid >> 6] = s; sb[tid >> 6] = q; }
  __syncthreads();
  s = sa[0] + sa[1] + sa[2] + sa[3];
  q = sb[0] + sb[1] + sb[2] + sb[3];
  float mean = s * (1.f / D_);
  float var  = q * (1.f / D_) - mean * mean;
  float rstd = rsqrtf(var + 1e-5f);
  #pragma unroll
  for (int j = 0; j < 4; ++j)
    qln[c + j] = (v4[j] - mean) * rstd * lg[c + j] + lb[c + j];
  __syncthreads();
  #pragma unroll
  for (int j = 0; j < 4; ++j) {
    int idx = tid + j * 256; int h = idx >> 6, e = idx & 63;
    float acc = 0.f;
    for (int d = 0; d < DH_; ++d)
      acc += qln[(h << 6) + d] * Wq[((size_t)(h << 6) + d) * DH_ + e];
    Qp[idx] = acc;
  }
  __syncthreads();
  #pragma unroll
  for (int j = 0; j < 4; ++j) {
    int idx = tid + j * 256; int h = idx >> 6, d = idx & 63;
    float acc = 0.f;
    for (int e = 0; e < DH_; ++e)
      acc += Wk[((size_t)(h << 6) + d) * DH_ + e] * Qp[(h << 6) + e];
    qkb[(size_t)n * D_ + idx] = acc * 0.03125f;   // 1/sqrt(1024)
  }
}

// ---------------------------------------------------------------- standalone LN (+optional qk fold)
__global__ __launch_bounds__(256) void ln_fold(const float* __restrict__ src,
                                               const float* __restrict__ g,
                                               const float* __restrict__ b,
                                               const float* __restrict__ Wq,
                                               const float* __restrict__ Wk,
                                               float* __restrict__ dst) {
  int n = blockIdx.x, tid = threadIdx.x, c = tid * 4;
  __shared__ float qln[D_], Qp[D_];
  float4 xv = *(const float4*)&src[(size_t)n * D_ + c];
  float v[4] = {xv.x, xv.y, xv.z, xv.w};
  if (Wq != nullptr) {
    ln_qk_epilogue(n, v, tid, g, b, Wq, Wk, dst, qln, Qp);
  } else {
    float s = v[0] + v[1] + v[2] + v[3];
    float q = v[0]*v[0] + v[1]*v[1] + v[2]*v[2] + v[3]*v[3];
    __shared__ float sa2[4], sb2[4];
    #pragma unroll
    for (int o = 32; o; o >>= 1) { s += __shfl_xor(s, o, 64); q += __shfl_xor(q, o, 64); }
    if ((tid & 63) == 0) { sa2[tid >> 6] = s; sb2[tid >> 6] = q; }
    __syncthreads();
    s = sa2[0] + sa2[1] + sa2[2] + sa2[3];
    q = sb2[0] + sb2[1] + sb2[2] + sb2[3];
    float mean = s * (1.f / D_);
    float var  = q * (1.f / D_) - mean * mean;
    float rstd = rsqrtf(var + 1e-5f);
    #pragma unroll
    for (int j = 0; j < 4; ++j)
      dst[(size_t)n * D_ + c + j] = (v[j] - mean) * rstd * g[c + j] + b[c + j];
  }
}

// ---------------------------------------------------------------- fused split-K GEMM + ticketed combine/epilogue
// MODE 0: out1 = v + bias
// MODE 1: out1 = relu(v+bias); if out2: out2[(row*NB+slot)*D+col] = same
// MODE 2 (NC=2048): col<1024: out1 = sigmoid(v)*xb ; col>=1024: out2 = sigmoid(v - bias[col-1024])
// MODE 3: out1 = (1-z)*xb + z*tanh(v); if out2: slot>=0 ? out2[(row*NB+slot)*D+col] : out2[row*D+col]
template<int NC, int MODE>
__global__ __launch_bounds__(256) void gemm_f(const float* __restrict__ A1,
                                              const float* __restrict__ B1a,
                                              const float* __restrict__ B1b,
                                              const float* __restrict__ A2,
                                              const float* __restrict__ B2a,
                                              const float* __restrict__ B2b,
                                              const float* __restrict__ bias,
                                              const float* __restrict__ xb,
                                              const float* __restrict__ zin,
                                              float* __restrict__ Cpart,
                                              float* __restrict__ out1,
                                              float* __restrict__ out2,
                                              int slot, int* __restrict__ cnt) {
  int colg = blockIdx.x * 32 + (threadIdx.x & 31);
  int row0 = (threadIdx.x >> 5) * 16;
  int k0   = blockIdx.y * (D_ / KS_);
  const float* B1 = B1a;
  const float* B2 = B2a;
  int col = colg;
  if (NC == 2048 && colg >= 1024) { B1 = B1b; B2 = B2b; col = colg - 1024; }
  float acc[16];
  #pragma unroll
  for (int r = 0; r < 16; ++r) acc[r] = 0.f;
  for (int k = k0; k < k0 + (D_ / KS_); k += 4) {
    float b0 = B1[(size_t)(k + 0) * D_ + col];
    float b1 = B1[(size_t)(k + 1) * D_ + col];
    float b2 = B1[(size_t)(k + 2) * D_ + col];
    float b3 = B1[(size_t)(k + 3) * D_ + col];
    #pragma unroll
    for (int r = 0; r < 16; ++r) {
      float4 a = *(const float4*)&A1[(size_t)(row0 + r) * D_ + k];
      acc[r] += a.x * b0 + a.y * b1 + a.z * b2 + a.w * b3;
    }
  }
  if (A2 != nullptr) {
    for (int k = k0; k < k0 + (D_ / KS_); k += 4) {
      float b0 = B2[(size_t)(k + 0) * D_ + col];
      float b1 = B2[(size_t)(k + 1) * D_ + col];
      float b2 = B2[(size_t)(k + 2) * D_ + col];
      float b3 = B2[(size_t)(k + 3) * D_ + col];
      #pragma unroll
      for (int r = 0; r < 16; ++r) {
        float4 a = *(const float4*)&A2[(size_t)(row0 + r) * D_ + k];
        acc[r] += a.x * b0 + a.y * b1 + a.z * b2 + a.w * b3;
      }
    }
  }
  #pragma unroll
  for (int r = 0; r < 16; ++r)
    Cpart[(size_t)blockIdx.y * (N_ * NC) + (size_t)(row0 + r) * NC + colg] = acc[r];

  // ---- ticket: last split-block for this col-tile combines + epilogue
  __threadfence();
  __shared__ int tick;
  if (threadIdx.x == 0) tick = atomicAdd(&cnt[blockIdx.x], 1);
  __syncthreads();
  if (tick == KS_ - 1) {
    __threadfence();
    const volatile float* vp = (const volatile float*)Cpart;
    for (int r = 0; r < 16; ++r) {
      int row = row0 + r;
      float v = 0.f;
      #pragma unroll
      for (int s = 0; s < KS_; ++s)
        v += vp[(size_t)s * (N_ * NC) + (size_t)row * NC + colg];
      size_t idx = (size_t)row * D_ + col;
      if (MODE == 0) {
        out1[idx] = v + bias[colg];
      } else if (MODE == 1) {
        float val = fmaxf(v + bias[colg], 0.f);
        out1[idx] = val;
        if (out2 != nullptr) out2[((size_t)row * NB_ + slot) * D_ + colg] = val;
      } else if (MODE == 2) {
        if (colg < 1024) out1[idx] = (1.f / (1.f + __expf(-v))) * xb[idx];
        else             out2[idx] = 1.f / (1.f + __expf(-(v - bias[col])));
      } else {  // MODE 3
        float z = zin[idx], xx = xb[idx];
        float val = (1.f - z) * xx + z * tanhf(v);
        out1[idx] = val;
        if (out2 != nullptr) {
          size_t bi = (slot >= 0) ? (((size_t)row * NB_ + slot) * D_ + colg) : idx;
          out2[bi] = val;
        }
      }
    }
    if (threadIdx.x == 0) cnt[blockIdx.x] = 0;
  }
}

// ---------------------------------------------------------------- streaming attention + ticketed merge/V-proj
__global__ __launch_bounds__(256, 4) void attn_stream(
    const float* __restrict__ mem, const float* __restrict__ pos,
    const int* __restrict__ mask, const int* __restrict__ midx,
    const float* __restrict__ qkv, const float* __restrict__ lng,
    const float* __restrict__ lnb, const float* __restrict__ Wv, int blk,
    float* __restrict__ pav, float* __restrict__ pm, float* __restrict__ ps,
    float* __restrict__ tb, int* __restrict__ acnt)
{
  const int n    = blockIdx.y;
  const int w    = threadIdx.x >> 6;
  const int lane = threadIdx.x & 63;
  const int vc   = blockIdx.x * 4 + w;       // 0..31
  const int l0   = vc * (L_ / NCV_);         // 16 rows per wave
  const int d0   = lane * 16;

  float g[16], bv[16], qv[16];
  #pragma unroll
  for (int j = 0; j < 4; ++j) {
    float4 t0 = *(const float4*)&lng[d0 + 4 * j];
    g[4*j+0] = t0.x; g[4*j+1] = t0.y; g[4*j+2] = t0.z; g[4*j+3] = t0.w;
    float4 t1 = *(const float4*)&lnb[d0 + 4 * j];
    bv[4*j+0] = t1.x; bv[4*j+1] = t1.y; bv[4*j+2] = t1.z; bv[4*j+3] = t1.w;
    float4 t2 = *(const float4*)&qkv[(size_t)n * D_ + d0 + 4 * j];
    qv[4*j+0] = t2.x; qv[4*j+1] = t2.y; qv[4*j+2] = t2.z; qv[4*j+3] = t2.w;
  }
  float m_run = -INFINITY, s_run = 0.f;
  float av[16];
  #pragma unroll
  for (int j = 0; j < 16; ++j) av[j] = 0.f;

  for (int l = l0; l < l0 + (L_ / NCV_); ++l) {
    if (mask[(size_t)n * L_ + l] == 0) continue;   // wave-uniform
    const float* xr = &mem[(((size_t)n * L_ + l) * NB_ + blk) * D_ + d0];
    const int tt = midx[(size_t)n * L_ + l];
    const float* pr = &pos[(size_t)tt * D_ + d0];
    float xv[16];
    #pragma unroll
    for (int j = 0; j < 4; ++j) {
      float4 a = *(const float4*)&xr[4 * j];
      float4 p = *(const float4*)&pr[4 * j];
      xv[4*j+0] = a.x + p.x; xv[4*j+1] = a.y + p.y;
      xv[4*j+2] = a.z + p.z; xv[4*j+3] = a.w + p.w;
    }
    float s1 = 0.f, s2 = 0.f;
    #pragma unroll
    for (int j = 0; j < 16; ++j) { s1 += xv[j]; s2 += xv[j] * xv[j]; }
    #pragma unroll
    for (int o = 32; o; o >>= 1) { s1 += __shfl_xor(s1, o, 64); s2 += __shfl_xor(s2, o, 64); }
    float mean = s1 * (1.f / D_);
    float var  = s2 * (1.f / D_) - mean * mean;
    float rstd = rsqrtf(var + 1e-5f);
    float e = 0.f;
    float y[16];
    #pragma unroll
    for (int j = 0; j < 16; ++j) {
      y[j] = (xv[j] - mean) * rstd * g[j] + bv[j];
      e += y[j] * qv[j];
    }
    e += __shfl_xor(e, 1, 64);
    e += __shfl_xor(e, 2, 64);     // 4-lane head group all hold full e
    float mn = fmaxf(m_run, e);
    float al = __expf(m_run - mn);
    float pw = __expf(e - mn);
    s_run = s_run * al + pw;
    #pragma unroll
    for (int j = 0; j < 16; ++j) av[j] = av[j] * al + pw * y[j];
    m_run = mn;
  }
  size_t base = ((size_t)n * NCV_ + vc) * D_ + d0;
  #pragma unroll
  for (int j = 0; j < 16; ++j) pav[base + j] = av[j];
  if ((lane & 3) == 0) {
    size_t mb = ((size_t)n * NCV_ + vc) * H_ + (lane >> 2);
    pm[mb] = m_run;
    ps[mb] = s_run;
  }

  // ---- ticket: last of 8 blocks for this sample merges chunks + V-projection
  __threadfence();
  __shared__ int tick;
  if (threadIdx.x == 0) tick = atomicAdd(&acnt[n], 1);
  __syncthreads();
  if (tick == 7) {
    __threadfence();
    int tid = threadIdx.x;
    int dd = tid * 4; int h = tid >> 4;
    const volatile float* vpm  = (const volatile float*)pm;
    const volatile float* vps  = (const volatile float*)ps;
    const volatile float* vpav = (const volatile float*)pav;
    float M = -INFINITY;
    for (int c = 0; c < NCV_; ++c) M = fmaxf(M, vpm[((size_t)n * NCV_ + c) * H_ + h]);
    float S = 0.f, a0 = 0.f, a1 = 0.f, a2 = 0.f, a3 = 0.f;
    if (M > -INFINITY) {
      for (int c = 0; c < NCV_; ++c) {
        float mc = vpm[((size_t)n * NCV_ + c) * H_ + h];
        if (mc == -INFINITY) continue;
        float wgt = __expf(mc - M);
        S += vps[((size_t)n * NCV_ + c) * H_ + h] * wgt;
        size_t ab = ((size_t)n * NCV_ + c) * D_ + dd;
        a0 += vpav[ab + 0] * wgt; a1 += vpav[ab + 1] * wgt;
        a2 += vpav[ab + 2] * wgt; a3 += vpav[ab + 3] * wgt;
      }
    }
    float inv = (S > 0.f) ? 1.f / S : 0.f;
    __shared__ float att[D_];
    att[dd + 0] = a0 * inv; att[dd + 1] = a1 * inv;
    att[dd + 2] = a2 * inv; att[dd + 3] = a3 * inv;
    __syncthreads();
    #pragma unroll
    for (int j = 0; j < 4; ++j) {
      int idx = tid + j * 256; int hh = idx >> 6, e = idx & 63;
      float acc = 0.f;
      for (int d = 0; d < DH_; ++d)
        acc += att[(hh << 6) + d] * Wv[((size_t)(hh << 6) + d) * DH_ + e];
      tb[(size_t)n * D_ + idx] = acc;
    }
    if (tid == 0) acnt[n] = 0;
  }
}

// ----------------------------------------------------------------
extern "C" void kernel_launch(void* const* d_in, const int* in_sizes, int n_in,
                              void* d_out, int out_size, void* d_ws, size_t ws_size,
                              hipStream_t stream) {
  const float* x    = (const float*)d_in[0];
  const float* mem  = (const float*)d_in[1];
  const int*   mask = (const int*)d_in[2];
  const int*   midx = (const int*)d_in[3];
  const float* We   = (const float*)d_in[5];
  const float* be   = (const float*)d_in[6];
  const float* Wq   = (const float*)d_in[7];
  const float* Wk   = (const float*)d_in[8];
  const float* Wv   = (const float*)d_in[9];
  const float* Wo   = (const float*)d_in[10];
  const float* bo   = (const float*)d_in[11];
  const float* Wfc  = (const float*)d_in[12];
  const float* bfc  = (const float*)d_in[13];
  const float* ln1g = (const float*)d_in[14];
  const float* ln1b = (const float*)d_in[15];
  const float* ln2g = (const float*)d_in[16];
  const float* ln2b = (const float*)d_in[17];
  const float* lnkg = (const float*)d_in[18];
  const float* lnkb = (const float*)d_in[19];
  const float* g1w[7]; for (int j = 0; j < 7; ++j) g1w[j] = (const float*)d_in[20 + j];
  const float* g2w[7]; for (int j = 0; j < 7; ++j) g2w[j] = (const float*)d_in[27 + j];
  float* out = (float*)d_out;
  float* out_li = out + (size_t)N_ * D_;   // layer_inputs region (N, NB, D)

  float* ws   = (float*)d_ws;
  int*   cnt  = (int*)ws; ws += 256;       // [0..63] gemm tiles, [64..191] attn samples
  int*   acnt = cnt + 64;
  float* pos  = ws; ws += (size_t)T_ * D_;
  float* hcur = ws; ws += N_ * D_;
  float* qkb  = ws; ws += N_ * D_;
  float* tb   = ws; ws += N_ * D_;
  float* ao   = ws; ws += N_ * D_;
  float* rq   = ws; ws += N_ * D_;
  float* zb   = ws; ws += N_ * D_;
  float* h1   = ws; ws += N_ * D_;
  float* hl   = ws; ws += N_ * D_;
  float* fwd  = ws; ws += N_ * D_;
  float* gpart = ws; ws += (size_t)KS_ * N_ * 2048;
  float* pav   = ws; ws += (size_t)N_ * NCV_ * D_;
  float* pm    = ws; ws += (size_t)N_ * NCV_ * H_;
  float* ps    = ws; ws += (size_t)N_ * NCV_ * H_;

  const dim3 gp1(32, KS_);
  const dim3 gp2(64, KS_);
  const dim3 at_grid(NCV_ / 4, N_);

  pos_kernel<<<T_, 512, 0, stream>>>(pos, cnt);

  // embed: h0 = relu(x@We + be) -> hcur + out_li slot 0
  gemm_f<1024, 1><<<gp1, 256, 0, stream>>>(x, We, nullptr, nullptr, nullptr, nullptr,
                                           be, nullptr, nullptr, gpart, hcur, out_li, 0, cnt);
  ln_fold<<<N_, 256, 0, stream>>>(hcur, ln1g, ln1b, Wq, Wk, qkb);

  for (int i = 0; i < NB_; ++i) {
    size_t oD  = (size_t)i * D_;
    size_t oDD = (size_t)i * D_ * D_;
    size_t oH  = (size_t)i * H_ * DH_ * DH_;

    attn_stream<<<at_grid, 256, 0, stream>>>(mem, pos, mask, midx, qkb,
                                             lnkg + oD, lnkb + oD, Wv + oH, i,
                                             pav, pm, ps, tb, acnt);

    gemm_f<1024, 0><<<gp1, 256, 0, stream>>>(tb, Wo + oDD, nullptr, nullptr, nullptr, nullptr,
                                             bo + oD, nullptr, nullptr, gpart, ao, nullptr, -1, cnt);

    // GRU1: x=hcur, y=ao
    gemm_f<2048, 2><<<gp2, 256, 0, stream>>>(ao, g1w[0] + oDD, g1w[2] + oDD,
                                             hcur, g1w[1] + oDD, g1w[3] + oDD,
                                             g1w[6] + oD, hcur, nullptr, gpart, rq, zb, -1, cnt);
    gemm_f<1024, 3><<<gp1, 256, 0, stream>>>(ao, g1w[4] + oDD, nullptr,
                                             rq, g1w[5] + oDD, nullptr,
                                             nullptr, hcur, zb, gpart, h1, nullptr, -1, cnt);
    ln_fold<<<N_, 256, 0, stream>>>(h1, ln2g + oD, ln2b + oD, nullptr, nullptr, hl);

    gemm_f<1024, 1><<<gp1, 256, 0, stream>>>(hl, Wfc + oDD, nullptr, nullptr, nullptr, nullptr,
                                             bfc + oD, nullptr, nullptr, gpart, fwd, nullptr, 0, cnt);

    // GRU2: x=h1, y=fwd
    gemm_f<2048, 2><<<gp2, 256, 0, stream>>>(fwd, g2w[0] + oDD, g2w[2] + oDD,
                                             h1, g2w[1] + oDD, g2w[3] + oDD,
                                             g2w[6] + oD, h1, nullptr, gpart, rq, zb, -1, cnt);
    bool last = (i == NB_ - 1);
    float* outp = last ? out : out_li;
    int slot = last ? -1 : (i + 1);
    gemm_f<1024, 3><<<gp1, 256, 0, stream>>>(fwd, g2w[4] + oDD, nullptr,
                                             rq, g2w[5] + oDD, nullptr,
                                             nullptr, h1, zb, gpart, hcur, outp, slot, cnt);
    if (!last)
      ln_fold<<<N_, 256, 0, stream>>>(hcur, ln1g + oD + D_, ln1b + oD + D_,
                                      Wq + oH + H_ * DH_ * DH_, Wk + oH + H_ * DH_ * DH_, qkb);
  }
}

// Round 6
// 1316.793 us; speedup vs baseline: 3.5535x; 3.5535x over previous
//
#include <hip/hip_runtime.h>
#include <hip/hip_bf16.h>

#define N_   128
#define L_   512
#define NB_  4
#define D_   1024
#define H_   16
#define DH_  64
#define IN_  1024
#define T_   512

#define KS_  16      // GEMM K-splits (Kc = 64) -> 512 blocks = 2/CU
#define NCV_ 32      // attention chunks per sample (16 rows each)

// ---------------------------------------------------------------- pos table
__global__ __launch_bounds__(512) void pos_kernel(float* __restrict__ pos) {
  int t = blockIdx.x;          // 0..511
  int j = threadIdx.x;         // 0..511
  float seq = (float)(T_ - 1 - t);
  float ex  = (float)(2 * j) * (1.0f / (float)D_);
  float inv = expf(-ex * 9.210340371976184f);   // 10000^(-2j/D)
  float si  = seq * inv;
  pos[(size_t)t * D_ + j]        = sinf(si);
  pos[(size_t)t * D_ + 512 + j]  = cosf(si);
}

// ---------------------------------------------------------------- split-K GEMM partials, LDS-staged A
// NC=1024: C = A1@B1a [+ A2@B2a]
// NC=2048: C[:, :1024] = A1@B1a [+ A2@B2a] ; C[:, 1024:] = A1@B1b [+ A2@B2b]
template<int NC, bool HAS2>
__global__ __launch_bounds__(256) void gemm_part_t(const float* __restrict__ A1,
                                                   const float* __restrict__ B1a,
                                                   const float* __restrict__ B1b,
                                                   const float* __restrict__ A2,
                                                   const float* __restrict__ B2a,
                                                   const float* __restrict__ B2b,
                                                   float* __restrict__ Cpart) {
  constexpr int KC = D_ / KS_;          // 64
  __shared__ float As[N_ * KC];         // 32 KB
  int colg = blockIdx.x * 32 + (threadIdx.x & 31);
  int row0 = (threadIdx.x >> 5) * 16;
  int k0   = blockIdx.y * KC;
  const float* B1 = B1a;
  const float* B2 = B2a;
  int col = colg;
  if (NC == 2048 && colg >= 1024) { B1 = B1b; B2 = B2b; col = colg - 1024; }

  float acc[16];
  #pragma unroll
  for (int r = 0; r < 16; ++r) acc[r] = 0.f;

  #pragma unroll
  for (int pass = 0; pass < (HAS2 ? 2 : 1); ++pass) {
    const float* A = pass ? A2 : A1;
    const float* B = pass ? B2 : B1;
    if (pass) __syncthreads();          // protect As reuse
    #pragma unroll
    for (int i = 0; i < 8; ++i) {       // stage A[0:128, k0:k0+64]
      int f = threadIdx.x + i * 256;    // float4 index
      int row = f >> 4, kk = (f & 15) * 4;
      *(float4*)&As[row * KC + kk] = *(const float4*)&A[(size_t)row * D_ + k0 + kk];
    }
    __syncthreads();
    #pragma unroll 2
    for (int kk = 0; kk < KC; kk += 4) {
      float b0 = B[(size_t)(k0 + kk + 0) * D_ + col];
      float b1 = B[(size_t)(k0 + kk + 1) * D_ + col];
      float b2 = B[(size_t)(k0 + kk + 2) * D_ + col];
      float b3 = B[(size_t)(k0 + kk + 3) * D_ + col];
      #pragma unroll
      for (int r = 0; r < 16; ++r) {
        float4 a = *(const float4*)&As[(row0 + r) * KC + kk];   // LDS broadcast
        acc[r] += a.x * b0 + a.y * b1 + a.z * b2 + a.w * b3;
      }
    }
  }
  #pragma unroll
  for (int r = 0; r < 16; ++r)
    Cpart[(size_t)blockIdx.y * (N_ * NC) + (size_t)(row0 + r) * NC + colg] = acc[r];
}

// ---------------------------------------------------------------- LN + qk fold (device helper)
__device__ __forceinline__ void ln_qk_epilogue(int n, const float* v4, int tid,
                                               const float* __restrict__ lg,
                                               const float* __restrict__ lb,
                                               const float* __restrict__ Wq,
                                               const float* __restrict__ Wk,
                                               float* __restrict__ qkb,
                                               float* qln, float* Qp /*LDS 1024 each*/) {
  int c = tid * 4;
  float s = v4[0] + v4[1] + v4[2] + v4[3];
  float q = v4[0]*v4[0] + v4[1]*v4[1] + v4[2]*v4[2] + v4[3]*v4[3];
  __shared__ float sa[4], sb[4];
  #pragma unroll
  for (int o = 32; o; o >>= 1) { s += __shfl_xor(s, o, 64); q += __shfl_xor(q, o, 64); }
  if ((tid & 63) == 0) { sa[tid >> 6] = s; sb[tid >> 6] = q; }
  __syncthreads();
  s = sa[0] + sa[1] + sa[2] + sa[3];
  q = sb[0] + sb[1] + sb[2] + sb[3];
  float mean = s * (1.f / D_);
  float var  = q * (1.f / D_) - mean * mean;
  float rstd = rsqrtf(var + 1e-5f);
  #pragma unroll
  for (int j = 0; j < 4; ++j)
    qln[c + j] = (v4[j] - mean) * rstd * lg[c + j] + lb[c + j];
  __syncthreads();
  #pragma unroll
  for (int j = 0; j < 4; ++j) {
    int idx = tid + j * 256; int h = idx >> 6, e = idx & 63;
    float acc = 0.f;
    for (int d = 0; d < DH_; ++d)
      acc += qln[(h << 6) + d] * Wq[((size_t)(h << 6) + d) * DH_ + e];
    Qp[idx] = acc;
  }
  __syncthreads();
  #pragma unroll
  for (int j = 0; j < 4; ++j) {
    int idx = tid + j * 256; int h = idx >> 6, d = idx & 63;
    float acc = 0.f;
    for (int e = 0; e < DH_; ++e)
      acc += Wk[((size_t)(h << 6) + d) * DH_ + e] * Qp[(h << 6) + e];
    qkb[(size_t)n * D_ + idx] = acc * 0.03125f;   // 1/sqrt(1024)
  }
}

// ---------------------------------------------------------------- embed combine: relu(v+be) -> hcur, out_li[0], LN1+qk
__global__ __launch_bounds__(256) void comb_embed_lnqk(const float* __restrict__ Cp,
                                                       const float* __restrict__ bias,
                                                       const float* __restrict__ lg,
                                                       const float* __restrict__ lb,
                                                       const float* __restrict__ Wq,
                                                       const float* __restrict__ Wk,
                                                       float* __restrict__ hcur,
                                                       float* __restrict__ out_li,
                                                       float* __restrict__ qkb) {
  int n = blockIdx.x, tid = threadIdx.x, c = tid * 4;
  __shared__ float qln[D_], Qp[D_];
  float v[4];
  #pragma unroll
  for (int j = 0; j < 4; ++j) {
    float acc = 0.f;
    #pragma unroll
    for (int s = 0; s < KS_; ++s) acc += Cp[(size_t)s * (N_ * D_) + (size_t)n * D_ + c + j];
    v[j] = fmaxf(acc + bias[c + j], 0.f);
    hcur[(size_t)n * D_ + c + j] = v[j];
    out_li[((size_t)n * NB_ + 0) * D_ + c + j] = v[j];
  }
  ln_qk_epilogue(n, v, tid, lg, lb, Wq, Wk, qkb, qln, Qp);
}

// ---------------------------------------------------------------- streaming attention (flash-decode, online softmax)
__global__ __launch_bounds__(256) void attn_stream(
    const float* __restrict__ mem, const float* __restrict__ pos,
    const int* __restrict__ mask, const int* __restrict__ midx,
    const float* __restrict__ qkv, const float* __restrict__ lng,
    const float* __restrict__ lnb, int blk,
    float* __restrict__ pav, float* __restrict__ pm, float* __restrict__ ps)
{
  const int n    = blockIdx.y;
  const int w    = threadIdx.x >> 6;
  const int lane = threadIdx.x & 63;
  const int vc   = blockIdx.x * 4 + w;       // 0..31
  const int l0   = vc * (L_ / NCV_);         // 16 rows per wave
  const int d0   = lane * 16;

  float g[16], bv[16], qv[16];
  #pragma unroll
  for (int j = 0; j < 4; ++j) {
    float4 t0 = *(const float4*)&lng[d0 + 4 * j];
    g[4*j+0] = t0.x; g[4*j+1] = t0.y; g[4*j+2] = t0.z; g[4*j+3] = t0.w;
    float4 t1 = *(const float4*)&lnb[d0 + 4 * j];
    bv[4*j+0] = t1.x; bv[4*j+1] = t1.y; bv[4*j+2] = t1.z; bv[4*j+3] = t1.w;
    float4 t2 = *(const float4*)&qkv[(size_t)n * D_ + d0 + 4 * j];
    qv[4*j+0] = t2.x; qv[4*j+1] = t2.y; qv[4*j+2] = t2.z; qv[4*j+3] = t2.w;
  }
  float m_run = -INFINITY, s_run = 0.f;
  float av[16];
  #pragma unroll
  for (int j = 0; j < 16; ++j) av[j] = 0.f;

  for (int l = l0; l < l0 + (L_ / NCV_); ++l) {
    if (mask[(size_t)n * L_ + l] == 0) continue;   // wave-uniform
    const float* xr = &mem[(((size_t)n * L_ + l) * NB_ + blk) * D_ + d0];
    const int tt = midx[(size_t)n * L_ + l];
    const float* pr = &pos[(size_t)tt * D_ + d0];
    float xv[16];
    #pragma unroll
    for (int j = 0; j < 4; ++j) {
      float4 a = *(const float4*)&xr[4 * j];
      float4 p = *(const float4*)&pr[4 * j];
      xv[4*j+0] = a.x + p.x; xv[4*j+1] = a.y + p.y;
      xv[4*j+2] = a.z + p.z; xv[4*j+3] = a.w + p.w;
    }
    float s1 = 0.f, s2 = 0.f;
    #pragma unroll
    for (int j = 0; j < 16; ++j) { s1 += xv[j]; s2 += xv[j] * xv[j]; }
    #pragma unroll
    for (int o = 32; o; o >>= 1) { s1 += __shfl_xor(s1, o, 64); s2 += __shfl_xor(s2, o, 64); }
    float mean = s1 * (1.f / D_);
    float var  = s2 * (1.f / D_) - mean * mean;
    float rstd = rsqrtf(var + 1e-5f);
    float e = 0.f;
    float y[16];
    #pragma unroll
    for (int j = 0; j < 16; ++j) {
      y[j] = (xv[j] - mean) * rstd * g[j] + bv[j];
      e += y[j] * qv[j];
    }
    e += __shfl_xor(e, 1, 64);
    e += __shfl_xor(e, 2, 64);     // 4-lane head group all hold full e
    float mn = fmaxf(m_run, e);
    float al = __expf(m_run - mn);
    float pw = __expf(e - mn);
    s_run = s_run * al + pw;
    #pragma unroll
    for (int j = 0; j < 16; ++j) av[j] = av[j] * al + pw * y[j];
    m_run = mn;
  }
  size_t base = ((size_t)n * NCV_ + vc) * D_ + d0;
  #pragma unroll
  for (int j = 0; j < 16; ++j) pav[base + j] = av[j];
  if ((lane & 3) == 0) {
    size_t mb = ((size_t)n * NCV_ + vc) * H_ + (lane >> 2);
    pm[mb] = m_run;
    ps[mb] = s_run;
  }
}

// ---------------------------------------------------------------- merge chunks + V-projection -> tb
__global__ __launch_bounds__(256) void attn_fin(const float* __restrict__ pav,
                                                const float* __restrict__ pm,
                                                const float* __restrict__ ps,
                                                const float* __restrict__ Wv,
                                                float* __restrict__ tb) {
  int n = blockIdx.x, tid = threadIdx.x;
  int d0 = tid * 4; int h = tid >> 4;
  float M = -INFINITY;
  for (int c = 0; c < NCV_; ++c) M = fmaxf(M, pm[((size_t)n * NCV_ + c) * H_ + h]);
  float S = 0.f, a0 = 0.f, a1 = 0.f, a2 = 0.f, a3 = 0.f;
  if (M > -INFINITY) {
    for (int c = 0; c < NCV_; ++c) {
      float mc = pm[((size_t)n * NCV_ + c) * H_ + h];
      if (mc == -INFINITY) continue;
      float wgt = __expf(mc - M);
      S += ps[((size_t)n * NCV_ + c) * H_ + h] * wgt;
      size_t ab = ((size_t)n * NCV_ + c) * D_ + d0;
      a0 += pav[ab + 0] * wgt; a1 += pav[ab + 1] * wgt;
      a2 += pav[ab + 2] * wgt; a3 += pav[ab + 3] * wgt;
    }
  }
  float inv = (S > 0.f) ? 1.f / S : 0.f;
  __shared__ float att[D_];
  att[d0 + 0] = a0 * inv; att[d0 + 1] = a1 * inv;
  att[d0 + 2] = a2 * inv; att[d0 + 3] = a3 * inv;
  __syncthreads();
  #pragma unroll
  for (int j = 0; j < 4; ++j) {
    int idx = tid + j * 256; int hh = idx >> 6, e = idx & 63;
    float acc = 0.f;
    for (int d = 0; d < DH_; ++d)
      acc += att[(hh << 6) + d] * Wv[((size_t)(hh << 6) + d) * DH_ + e];
    tb[(size_t)n * D_ + idx] = acc;
  }
}

// ---------------------------------------------------------------- elementwise combine: mode 0 relu(v+b), 1 v+b
__global__ __launch_bounds__(256) void comb_ew(const float* __restrict__ Cp,
                                               const float* __restrict__ bias,
                                               float* __restrict__ out, int mode) {
  int idx = blockIdx.x * 256 + threadIdx.x;
  int col = idx & (D_ - 1);
  float v = 0.f;
  #pragma unroll
  for (int s = 0; s < KS_; ++s) v += Cp[(size_t)s * (N_ * D_) + idx];
  v += bias[col];
  if (mode == 0) v = fmaxf(v, 0.f);
  out[idx] = v;
}

// ---------------------------------------------------------------- GRU r,z combine from 2048-wide partials
__global__ __launch_bounds__(256) void comb_rz(const float* __restrict__ Cp2,
                                               const float* __restrict__ bg,
                                               const float* __restrict__ xb,
                                               float* __restrict__ rq,
                                               float* __restrict__ zb) {
  int idx = blockIdx.x * 256 + threadIdx.x;      // 0..131071
  int row = idx >> 10, col = idx & (D_ - 1);
  float vr = 0.f, vz = 0.f;
  #pragma unroll
  for (int s = 0; s < KS_; ++s) {
    size_t b = (size_t)s * (N_ * 2048) + (size_t)row * 2048 + col;
    vr += Cp2[b];
    vz += Cp2[b + 1024];
  }
  rq[idx] = (1.f / (1.f + __expf(-vr))) * xb[idx];
  zb[idx] = 1.f / (1.f + __expf(-(vz - bg[col])));
}

// ---------------------------------------------------------------- GRU1 h combine + LN2 -> h1, hl
__global__ __launch_bounds__(256) void comb_h_ln(const float* __restrict__ Cp,
                                                 const float* __restrict__ zb,
                                                 const float* __restrict__ xb,
                                                 const float* __restrict__ lg,
                                                 const float* __restrict__ lb,
                                                 float* __restrict__ h1,
                                                 float* __restrict__ hl) {
  int n = blockIdx.x, tid = threadIdx.x, c = tid * 4;
  float v[4];
  float s = 0.f, q = 0.f;
  #pragma unroll
  for (int j = 0; j < 4; ++j) {
    float acc = 0.f;
    #pragma unroll
    for (int ss = 0; ss < KS_; ++ss) acc += Cp[(size_t)ss * (N_ * D_) + (size_t)n * D_ + c + j];
    float z = zb[(size_t)n * D_ + c + j];
    float x = xb[(size_t)n * D_ + c + j];
    v[j] = (1.f - z) * x + z * tanhf(acc);
    h1[(size_t)n * D_ + c + j] = v[j];
    s += v[j]; q += v[j] * v[j];
  }
  __shared__ float sa[4], sb[4];
  #pragma unroll
  for (int o = 32; o; o >>= 1) { s += __shfl_xor(s, o, 64); q += __shfl_xor(q, o, 64); }
  if ((tid & 63) == 0) { sa[tid >> 6] = s; sb[tid >> 6] = q; }
  __syncthreads();
  s = sa[0] + sa[1] + sa[2] + sa[3];
  q = sb[0] + sb[1] + sb[2] + sb[3];
  float mean = s * (1.f / D_);
  float var  = q * (1.f / D_) - mean * mean;
  float rstd = rsqrtf(var + 1e-5f);
  #pragma unroll
  for (int j = 0; j < 4; ++j)
    hl[(size_t)n * D_ + c + j] = (v[j] - mean) * rstd * lg[c + j] + lb[c + j];
}

// ---------------------------------------------------------------- GRU2 h combine -> hcur, out slot, optional LN1+qk(next)
__global__ __launch_bounds__(256) void comb_h2_lnqk(const float* __restrict__ Cp,
                                                    const float* __restrict__ zb,
                                                    const float* __restrict__ xb,
                                                    const float* __restrict__ lg,
                                                    const float* __restrict__ lb,
                                                    const float* __restrict__ Wq,
                                                    const float* __restrict__ Wk,
                                                    float* __restrict__ hcur,
                                                    float* __restrict__ outp,
                                                    int slot,
                                                    float* __restrict__ qkb) {
  int n = blockIdx.x, tid = threadIdx.x, c = tid * 4;
  __shared__ float qln[D_], Qp[D_];
  float v[4];
  #pragma unroll
  for (int j = 0; j < 4; ++j) {
    float acc = 0.f;
    #pragma unroll
    for (int ss = 0; ss < KS_; ++ss) acc += Cp[(size_t)ss * (N_ * D_) + (size_t)n * D_ + c + j];
    float z = zb[(size_t)n * D_ + c + j];
    float x = xb[(size_t)n * D_ + c + j];
    v[j] = (1.f - z) * x + z * tanhf(acc);
    hcur[(size_t)n * D_ + c + j] = v[j];
    size_t bi = (slot >= 0) ? (((size_t)n * NB_ + slot) * D_ + c + j)
                            : ((size_t)n * D_ + c + j);
    outp[bi] = v[j];
  }
  if (Wq != nullptr)
    ln_qk_epilogue(n, v, tid, lg, lb, Wq, Wk, qkb, qln, Qp);
}

// ----------------------------------------------------------------
extern "C" void kernel_launch(void* const* d_in, const int* in_sizes, int n_in,
                              void* d_out, int out_size, void* d_ws, size_t ws_size,
                              hipStream_t stream) {
  const float* x    = (const float*)d_in[0];
  const float* mem  = (const float*)d_in[1];
  const int*   mask = (const int*)d_in[2];
  const int*   midx = (const int*)d_in[3];
  const float* We   = (const float*)d_in[5];
  const float* be   = (const float*)d_in[6];
  const float* Wq   = (const float*)d_in[7];
  const float* Wk   = (const float*)d_in[8];
  const float* Wv   = (const float*)d_in[9];
  const float* Wo   = (const float*)d_in[10];
  const float* bo   = (const float*)d_in[11];
  const float* Wfc  = (const float*)d_in[12];
  const float* bfc  = (const float*)d_in[13];
  const float* ln1g = (const float*)d_in[14];
  const float* ln1b = (const float*)d_in[15];
  const float* ln2g = (const float*)d_in[16];
  const float* ln2b = (const float*)d_in[17];
  const float* lnkg = (const float*)d_in[18];
  const float* lnkb = (const float*)d_in[19];
  const float* g1w[7]; for (int j = 0; j < 7; ++j) g1w[j] = (const float*)d_in[20 + j];
  const float* g2w[7]; for (int j = 0; j < 7; ++j) g2w[j] = (const float*)d_in[27 + j];
  float* out = (float*)d_out;
  float* out_li = out + (size_t)N_ * D_;   // layer_inputs region (N, NB, D)

  float* ws   = (float*)d_ws;
  float* pos  = ws; ws += (size_t)T_ * D_;
  float* hcur = ws; ws += N_ * D_;
  float* qkb  = ws; ws += N_ * D_;
  float* tb   = ws; ws += N_ * D_;
  float* ao   = ws; ws += N_ * D_;
  float* rq   = ws; ws += N_ * D_;
  float* zb   = ws; ws += N_ * D_;
  float* h1   = ws; ws += N_ * D_;
  float* hl   = ws; ws += N_ * D_;
  float* fwd  = ws; ws += N_ * D_;
  float* gpart = ws; ws += (size_t)KS_ * N_ * 2048;   // 16 MB
  float* pav   = ws; ws += (size_t)N_ * NCV_ * D_;    // 16 MB
  float* pm    = ws; ws += (size_t)N_ * NCV_ * H_;
  float* ps    = ws; ws += (size_t)N_ * NCV_ * H_;

  const dim3 gp1(32, KS_);     // 1024-col GEMM, 512 blocks
  const dim3 gp2(64, KS_);     // 2048-col GEMM, 1024 blocks
  const dim3 at_grid(NCV_ / 4, N_);

  pos_kernel<<<T_, 512, 0, stream>>>(pos);

  // embed: h0 = relu(x@We + be); out_li[0]; LN1(layer0)+qk fold
  gemm_part_t<1024, false><<<gp1, 256, 0, stream>>>(x, We, nullptr, nullptr, nullptr, nullptr, gpart);
  comb_embed_lnqk<<<N_, 256, 0, stream>>>(gpart, be, ln1g, ln1b, Wq, Wk, hcur, out_li, qkb);

  for (int i = 0; i < NB_; ++i) {
    size_t oD  = (size_t)i * D_;
    size_t oDD = (size_t)i * D_ * D_;
    size_t oH  = (size_t)i * H_ * DH_ * DH_;

    attn_stream<<<at_grid, 256, 0, stream>>>(mem, pos, mask, midx, qkb,
                                             lnkg + oD, lnkb + oD, i, pav, pm, ps);
    attn_fin<<<N_, 256, 0, stream>>>(pav, pm, ps, Wv + oH, tb);

    gemm_part_t<1024, false><<<gp1, 256, 0, stream>>>(tb, Wo + oDD, nullptr, nullptr, nullptr, nullptr, gpart);
    comb_ew<<<512, 256, 0, stream>>>(gpart, bo + oD, ao, 1);

    // GRU1: x=hcur, y=ao
    gemm_part_t<2048, true><<<gp2, 256, 0, stream>>>(ao, g1w[0] + oDD, g1w[2] + oDD,
                                                     hcur, g1w[1] + oDD, g1w[3] + oDD, gpart);
    comb_rz<<<512, 256, 0, stream>>>(gpart, g1w[6] + oD, hcur, rq, zb);
    gemm_part_t<1024, true><<<gp1, 256, 0, stream>>>(ao, g1w[4] + oDD, nullptr,
                                                     rq, g1w[5] + oDD, nullptr, gpart);
    comb_h_ln<<<N_, 256, 0, stream>>>(gpart, zb, hcur, ln2g + oD, ln2b + oD, h1, hl);

    gemm_part_t<1024, false><<<gp1, 256, 0, stream>>>(hl, Wfc + oDD, nullptr, nullptr, nullptr, nullptr, gpart);
    comb_ew<<<512, 256, 0, stream>>>(gpart, bfc + oD, fwd, 0);

    // GRU2: x=h1, y=fwd
    gemm_part_t<2048, true><<<gp2, 256, 0, stream>>>(fwd, g2w[0] + oDD, g2w[2] + oDD,
                                                     h1, g2w[1] + oDD, g2w[3] + oDD, gpart);
    comb_rz<<<512, 256, 0, stream>>>(gpart, g2w[6] + oD, h1, rq, zb);
    gemm_part_t<1024, true><<<gp1, 256, 0, stream>>>(fwd, g2w[4] + oDD, nullptr,
                                                     rq, g2w[5] + oDD, nullptr, gpart);

    bool last = (i == NB_ - 1);
    float* outp = last ? out : out_li;
    int slot = last ? -1 : (i + 1);
    const float* nWq = last ? nullptr : (Wq + oH + H_ * DH_ * DH_);
    const float* nWk = last ? nullptr : (Wk + oH + H_ * DH_ * DH_);
    const float* nlg = last ? nullptr : (ln1g + oD + D_);
    const float* nlb = last ? nullptr : (ln1b + oD + D_);
    comb_h2_lnqk<<<N_, 256, 0, stream>>>(gpart, zb, h1, nlg, nlb, nWq, nWk,
                                         hcur, outp, slot, qkb);
  }
}

// Round 7
// 855.573 us; speedup vs baseline: 5.4691x; 1.5391x over previous
//
#include <hip/hip_runtime.h>
#include <hip/hip_bf16.h>

#define N_   128
#define L_   512
#define NB_  4
#define D_   1024
#define H_   16
#define DH_  64
#define IN_  1024
#define T_   512

#define KS_  16      // GEMM K-splits (Kc = 64)
#define NCV_ 32      // attention chunks per sample (16 rows each)

typedef __attribute__((ext_vector_type(8))) short short8v;   // 8 bf16 (4 VGPRs)
typedef __attribute__((ext_vector_type(4))) float float4v;   // MFMA accumulator

__device__ __forceinline__ short f2bf(float f) {             // RNE f32->bf16
  unsigned u = __float_as_uint(f);
  u += 0x7FFFu + ((u >> 16) & 1u);
  return (short)(u >> 16);
}
__device__ __forceinline__ int pack2(float a, float b) {
  return (int)(unsigned short)f2bf(a) | ((int)f2bf(b) << 16);
}

// ---------------------------------------------------------------- pos table
__global__ __launch_bounds__(512) void pos_kernel(float* __restrict__ pos) {
  int t = blockIdx.x;          // 0..511
  int j = threadIdx.x;         // 0..511
  float seq = (float)(T_ - 1 - t);
  float ex  = (float)(2 * j) * (1.0f / (float)D_);
  float inv = expf(-ex * 9.210340371976184f);   // 10000^(-2j/D)
  float si  = seq * inv;
  pos[(size_t)t * D_ + j]        = sinf(si);
  pos[(size_t)t * D_ + 512 + j]  = cosf(si);
}

// ---------------------------------------------------------------- MFMA split-K GEMM partials
// Block: 256 thr = 4 waves; tile 128 rows x 64 cols; Kc = 64 per split.
// NC=1024: C = A1@B1a [+ A2@B2a]; NC=2048: cols>=1024 use B1b/B2b.
// A (f32, 128xD) and B (f32, DxNC-slice) converted to bf16 while staging.
#define LDA_ 72   // padded row (shorts) -> 144 B, 16B-aligned, bank-spread
template<int NC, bool HAS2>
__global__ __launch_bounds__(256) void gemm_part_t(const float* __restrict__ A1,
                                                   const float* __restrict__ B1a,
                                                   const float* __restrict__ B1b,
                                                   const float* __restrict__ A2,
                                                   const float* __restrict__ B2a,
                                                   const float* __restrict__ B2b,
                                                   float* __restrict__ Cpart) {
  constexpr int KC = D_ / KS_;            // 64
  __shared__ short As[N_ * LDA_];         // 128 x 72
  __shared__ short Bs[64 * LDA_];         // 64 cols x 72 (transposed: Bs[col][k])
  const int tid  = threadIdx.x;
  const int colg0 = blockIdx.x * 64;
  const int k0    = blockIdx.y * KC;
  const float* B1 = B1a;
  const float* B2 = B2a;
  int col0 = colg0;
  if (NC == 2048 && colg0 >= 1024) { B1 = B1b; B2 = B2b; col0 = colg0 - 1024; }

  const int wid  = tid >> 6;
  const int lane = tid & 63;
  const int lrow = lane & 15;
  const int lk8  = (lane >> 4) * 8;       // k-offset within 32-chunk
  const int wrow0 = wid * 32;

  float4v acc[2][4];
  #pragma unroll
  for (int a = 0; a < 2; ++a)
    #pragma unroll
    for (int b = 0; b < 4; ++b)
      acc[a][b] = (float4v){0.f, 0.f, 0.f, 0.f};

  // staging decomposition
  const int arow  = tid >> 1;             // A: 2 threads per row
  const int ahalf = (tid & 1) * 32;       // 32 k's each
  const int bcol  = tid & 63;             // B: thread owns one col,
  const int bkq   = (tid >> 6) * 16;      // 16 k's

  #pragma unroll
  for (int pass = 0; pass < (HAS2 ? 2 : 1); ++pass) {
    const float* A = pass ? A2 : A1;
    const float* B = pass ? B2 : B1;
    if (pass) __syncthreads();            // all reads of LDS done
    // ---- stage A[0:128, k0+0:64] -> bf16 As
    {
      const float* ap = &A[(size_t)arow * D_ + k0 + ahalf];
      short* dst = &As[arow * LDA_ + ahalf];
      #pragma unroll
      for (int j = 0; j < 8; ++j) {
        float4 v = *(const float4*)&ap[4 * j];
        *(int2*)&dst[4 * j] = make_int2(pack2(v.x, v.y), pack2(v.z, v.w));
      }
    }
    // ---- stage B[k0:k0+64, col0:col0+64] -> bf16 Bs[col][k]
    {
      int regs[8];
      #pragma unroll
      for (int j = 0; j < 8; ++j) {
        float v0 = B[(size_t)(k0 + bkq + 2 * j) * D_ + col0 + bcol];
        float v1 = B[(size_t)(k0 + bkq + 2 * j + 1) * D_ + col0 + bcol];
        regs[j] = pack2(v0, v1);
      }
      short* dst = &Bs[bcol * LDA_ + bkq];
      *(int4*)&dst[0] = make_int4(regs[0], regs[1], regs[2], regs[3]);
      *(int4*)&dst[8] = make_int4(regs[4], regs[5], regs[6], regs[7]);
    }
    __syncthreads();
    // ---- MFMA: 2 k-chunks of 32
    #pragma unroll
    for (int kk = 0; kk < KC; kk += 32) {
      short8v a0 = *(const short8v*)&As[(wrow0 + lrow)      * LDA_ + kk + lk8];
      short8v a1 = *(const short8v*)&As[(wrow0 + 16 + lrow) * LDA_ + kk + lk8];
      #pragma unroll
      for (int ct = 0; ct < 4; ++ct) {
        short8v bf = *(const short8v*)&Bs[(ct * 16 + lrow) * LDA_ + kk + lk8];
        acc[0][ct] = __builtin_amdgcn_mfma_f32_16x16x32_bf16(a0, bf, acc[0][ct], 0, 0, 0);
        acc[1][ct] = __builtin_amdgcn_mfma_f32_16x16x32_bf16(a1, bf, acc[1][ct], 0, 0, 0);
      }
    }
  }
  // ---- write partials: row=(lane>>4)*4+j, col=lane&15 within each 16x16 tile
  float* Cp = &Cpart[(size_t)blockIdx.y * (N_ * NC)];
  const int crow = (lane >> 4) * 4;
  const int ccol = lane & 15;
  #pragma unroll
  for (int rt = 0; rt < 2; ++rt)
    #pragma unroll
    for (int ct = 0; ct < 4; ++ct)
      #pragma unroll
      for (int j = 0; j < 4; ++j) {
        int row = wrow0 + rt * 16 + crow + j;
        int col = colg0 + ct * 16 + ccol;
        Cp[(size_t)row * NC + col] = acc[rt][ct][j];
      }
}

// ---------------------------------------------------------------- LN + qk fold (device helper)
__device__ __forceinline__ void ln_qk_epilogue(int n, const float* v4, int tid,
                                               const float* __restrict__ lg,
                                               const float* __restrict__ lb,
                                               const float* __restrict__ Wq,
                                               const float* __restrict__ Wk,
                                               float* __restrict__ qkb,
                                               float* qln, float* Qp /*LDS 1024 each*/) {
  int c = tid * 4;
  float s = v4[0] + v4[1] + v4[2] + v4[3];
  float q = v4[0]*v4[0] + v4[1]*v4[1] + v4[2]*v4[2] + v4[3]*v4[3];
  __shared__ float sa[4], sb[4];
  #pragma unroll
  for (int o = 32; o; o >>= 1) { s += __shfl_xor(s, o, 64); q += __shfl_xor(q, o, 64); }
  if ((tid & 63) == 0) { sa[tid >> 6] = s; sb[tid >> 6] = q; }
  __syncthreads();
  s = sa[0] + sa[1] + sa[2] + sa[3];
  q = sb[0] + sb[1] + sb[2] + sb[3];
  float mean = s * (1.f / D_);
  float var  = q * (1.f / D_) - mean * mean;
  float rstd = rsqrtf(var + 1e-5f);
  #pragma unroll
  for (int j = 0; j < 4; ++j)
    qln[c + j] = (v4[j] - mean) * rstd * lg[c + j] + lb[c + j];
  __syncthreads();
  #pragma unroll
  for (int j = 0; j < 4; ++j) {
    int idx = tid + j * 256; int h = idx >> 6, e = idx & 63;
    float acc = 0.f;
    for (int d = 0; d < DH_; ++d)
      acc += qln[(h << 6) + d] * Wq[((size_t)(h << 6) + d) * DH_ + e];
    Qp[idx] = acc;
  }
  __syncthreads();
  #pragma unroll
  for (int j = 0; j < 4; ++j) {
    int idx = tid + j * 256; int h = idx >> 6, d = idx & 63;
    float acc = 0.f;
    for (int e = 0; e < DH_; ++e)
      acc += Wk[((size_t)(h << 6) + d) * DH_ + e] * Qp[(h << 6) + e];
    qkb[(size_t)n * D_ + idx] = acc * 0.03125f;   // 1/sqrt(1024)
  }
}

// ---------------------------------------------------------------- embed combine: relu(v+be) -> hcur, out_li[0], LN1+qk
__global__ __launch_bounds__(256) void comb_embed_lnqk(const float* __restrict__ Cp,
                                                       const float* __restrict__ bias,
                                                       const float* __restrict__ lg,
                                                       const float* __restrict__ lb,
                                                       const float* __restrict__ Wq,
                                                       const float* __restrict__ Wk,
                                                       float* __restrict__ hcur,
                                                       float* __restrict__ out_li,
                                                       float* __restrict__ qkb) {
  int n = blockIdx.x, tid = threadIdx.x, c = tid * 4;
  __shared__ float qln[D_], Qp[D_];
  float v[4];
  #pragma unroll
  for (int j = 0; j < 4; ++j) {
    float acc = 0.f;
    #pragma unroll
    for (int s = 0; s < KS_; ++s) acc += Cp[(size_t)s * (N_ * D_) + (size_t)n * D_ + c + j];
    v[j] = fmaxf(acc + bias[c + j], 0.f);
    hcur[(size_t)n * D_ + c + j] = v[j];
    out_li[((size_t)n * NB_ + 0) * D_ + c + j] = v[j];
  }
  ln_qk_epilogue(n, v, tid, lg, lb, Wq, Wk, qkb, qln, Qp);
}

// ---------------------------------------------------------------- streaming attention (flash-decode, online softmax)
__global__ __launch_bounds__(256) void attn_stream(
    const float* __restrict__ mem, const float* __restrict__ pos,
    const int* __restrict__ mask, const int* __restrict__ midx,
    const float* __restrict__ qkv, const float* __restrict__ lng,
    const float* __restrict__ lnb, int blk,
    float* __restrict__ pav, float* __restrict__ pm, float* __restrict__ ps)
{
  const int n    = blockIdx.y;
  const int w    = threadIdx.x >> 6;
  const int lane = threadIdx.x & 63;
  const int vc   = blockIdx.x * 4 + w;       // 0..31
  const int l0   = vc * (L_ / NCV_);         // 16 rows per wave
  const int d0   = lane * 16;

  float g[16], bv[16], qv[16];
  #pragma unroll
  for (int j = 0; j < 4; ++j) {
    float4 t0 = *(const float4*)&lng[d0 + 4 * j];
    g[4*j+0] = t0.x; g[4*j+1] = t0.y; g[4*j+2] = t0.z; g[4*j+3] = t0.w;
    float4 t1 = *(const float4*)&lnb[d0 + 4 * j];
    bv[4*j+0] = t1.x; bv[4*j+1] = t1.y; bv[4*j+2] = t1.z; bv[4*j+3] = t1.w;
    float4 t2 = *(const float4*)&qkv[(size_t)n * D_ + d0 + 4 * j];
    qv[4*j+0] = t2.x; qv[4*j+1] = t2.y; qv[4*j+2] = t2.z; qv[4*j+3] = t2.w;
  }
  float m_run = -INFINITY, s_run = 0.f;
  float av[16];
  #pragma unroll
  for (int j = 0; j < 16; ++j) av[j] = 0.f;

  for (int l = l0; l < l0 + (L_ / NCV_); ++l) {
    if (mask[(size_t)n * L_ + l] == 0) continue;   // wave-uniform
    const float* xr = &mem[(((size_t)n * L_ + l) * NB_ + blk) * D_ + d0];
    const int tt = midx[(size_t)n * L_ + l];
    const float* pr = &pos[(size_t)tt * D_ + d0];
    float xv[16];
    #pragma unroll
    for (int j = 0; j < 4; ++j) {
      float4 a = *(const float4*)&xr[4 * j];
      float4 p = *(const float4*)&pr[4 * j];
      xv[4*j+0] = a.x + p.x; xv[4*j+1] = a.y + p.y;
      xv[4*j+2] = a.z + p.z; xv[4*j+3] = a.w + p.w;
    }
    float s1 = 0.f, s2 = 0.f;
    #pragma unroll
    for (int j = 0; j < 16; ++j) { s1 += xv[j]; s2 += xv[j] * xv[j]; }
    #pragma unroll
    for (int o = 32; o; o >>= 1) { s1 += __shfl_xor(s1, o, 64); s2 += __shfl_xor(s2, o, 64); }
    float mean = s1 * (1.f / D_);
    float var  = s2 * (1.f / D_) - mean * mean;
    float rstd = rsqrtf(var + 1e-5f);
    float e = 0.f;
    float y[16];
    #pragma unroll
    for (int j = 0; j < 16; ++j) {
      y[j] = (xv[j] - mean) * rstd * g[j] + bv[j];
      e += y[j] * qv[j];
    }
    e += __shfl_xor(e, 1, 64);
    e += __shfl_xor(e, 2, 64);     // 4-lane head group all hold full e
    float mn = fmaxf(m_run, e);
    float al = __expf(m_run - mn);
    float pw = __expf(e - mn);
    s_run = s_run * al + pw;
    #pragma unroll
    for (int j = 0; j < 16; ++j) av[j] = av[j] * al + pw * y[j];
    m_run = mn;
  }
  size_t base = ((size_t)n * NCV_ + vc) * D_ + d0;
  #pragma unroll
  for (int j = 0; j < 16; ++j) pav[base + j] = av[j];
  if ((lane & 3) == 0) {
    size_t mb = ((size_t)n * NCV_ + vc) * H_ + (lane >> 2);
    pm[mb] = m_run;
    ps[mb] = s_run;
  }
}

// ---------------------------------------------------------------- merge chunks + V-projection -> tb
__global__ __launch_bounds__(256) void attn_fin(const float* __restrict__ pav,
                                                const float* __restrict__ pm,
                                                const float* __restrict__ ps,
                                                const float* __restrict__ Wv,
                                                float* __restrict__ tb) {
  int n = blockIdx.x, tid = threadIdx.x;
  int d0 = tid * 4; int h = tid >> 4;
  float M = -INFINITY;
  for (int c = 0; c < NCV_; ++c) M = fmaxf(M, pm[((size_t)n * NCV_ + c) * H_ + h]);
  float S = 0.f, a0 = 0.f, a1 = 0.f, a2 = 0.f, a3 = 0.f;
  if (M > -INFINITY) {
    for (int c = 0; c < NCV_; ++c) {
      float mc = pm[((size_t)n * NCV_ + c) * H_ + h];
      if (mc == -INFINITY) continue;
      float wgt = __expf(mc - M);
      S += ps[((size_t)n * NCV_ + c) * H_ + h] * wgt;
      size_t ab = ((size_t)n * NCV_ + c) * D_ + d0;
      a0 += pav[ab + 0] * wgt; a1 += pav[ab + 1] * wgt;
      a2 += pav[ab + 2] * wgt; a3 += pav[ab + 3] * wgt;
    }
  }
  float inv = (S > 0.f) ? 1.f / S : 0.f;
  __shared__ float att[D_];
  att[d0 + 0] = a0 * inv; att[d0 + 1] = a1 * inv;
  att[d0 + 2] = a2 * inv; att[d0 + 3] = a3 * inv;
  __syncthreads();
  #pragma unroll
  for (int j = 0; j < 4; ++j) {
    int idx = tid + j * 256; int hh = idx >> 6, e = idx & 63;
    float acc = 0.f;
    for (int d = 0; d < DH_; ++d)
      acc += att[(hh << 6) + d] * Wv[((size_t)(hh << 6) + d) * DH_ + e];
    tb[(size_t)n * D_ + idx] = acc;
  }
}

// ---------------------------------------------------------------- elementwise combine: mode 0 relu(v+b), 1 v+b
__global__ __launch_bounds__(256) void comb_ew(const float* __restrict__ Cp,
                                               const float* __restrict__ bias,
                                               float* __restrict__ out, int mode) {
  int idx = blockIdx.x * 256 + threadIdx.x;
  int col = idx & (D_ - 1);
  float v = 0.f;
  #pragma unroll
  for (int s = 0; s < KS_; ++s) v += Cp[(size_t)s * (N_ * D_) + idx];
  v += bias[col];
  if (mode == 0) v = fmaxf(v, 0.f);
  out[idx] = v;
}

// ---------------------------------------------------------------- GRU r,z combine from 2048-wide partials
__global__ __launch_bounds__(256) void comb_rz(const float* __restrict__ Cp2,
                                               const float* __restrict__ bg,
                                               const float* __restrict__ xb,
                                               float* __restrict__ rq,
                                               float* __restrict__ zb) {
  int idx = blockIdx.x * 256 + threadIdx.x;      // 0..131071
  int row = idx >> 10, col = idx & (D_ - 1);
  float vr = 0.f, vz = 0.f;
  #pragma unroll
  for (int s = 0; s < KS_; ++s) {
    size_t b = (size_t)s * (N_ * 2048) + (size_t)row * 2048 + col;
    vr += Cp2[b];
    vz += Cp2[b + 1024];
  }
  rq[idx] = (1.f / (1.f + __expf(-vr))) * xb[idx];
  zb[idx] = 1.f / (1.f + __expf(-(vz - bg[col])));
}

// ---------------------------------------------------------------- GRU1 h combine + LN2 -> h1, hl
__global__ __launch_bounds__(256) void comb_h_ln(const float* __restrict__ Cp,
                                                 const float* __restrict__ zb,
                                                 const float* __restrict__ xb,
                                                 const float* __restrict__ lg,
                                                 const float* __restrict__ lb,
                                                 float* __restrict__ h1,
                                                 float* __restrict__ hl) {
  int n = blockIdx.x, tid = threadIdx.x, c = tid * 4;
  float v[4];
  float s = 0.f, q = 0.f;
  #pragma unroll
  for (int j = 0; j < 4; ++j) {
    float acc = 0.f;
    #pragma unroll
    for (int ss = 0; ss < KS_; ++ss) acc += Cp[(size_t)ss * (N_ * D_) + (size_t)n * D_ + c + j];
    float z = zb[(size_t)n * D_ + c + j];
    float x = xb[(size_t)n * D_ + c + j];
    v[j] = (1.f - z) * x + z * tanhf(acc);
    h1[(size_t)n * D_ + c + j] = v[j];
    s += v[j]; q += v[j] * v[j];
  }
  __shared__ float sa[4], sb[4];
  #pragma unroll
  for (int o = 32; o; o >>= 1) { s += __shfl_xor(s, o, 64); q += __shfl_xor(q, o, 64); }
  if ((tid & 63) == 0) { sa[tid >> 6] = s; sb[tid >> 6] = q; }
  __syncthreads();
  s = sa[0] + sa[1] + sa[2] + sa[3];
  q = sb[0] + sb[1] + sb[2] + sb[3];
  float mean = s * (1.f / D_);
  float var  = q * (1.f / D_) - mean * mean;
  float rstd = rsqrtf(var + 1e-5f);
  #pragma unroll
  for (int j = 0; j < 4; ++j)
    hl[(size_t)n * D_ + c + j] = (v[j] - mean) * rstd * lg[c + j] + lb[c + j];
}

// ---------------------------------------------------------------- GRU2 h combine -> hcur, out slot, optional LN1+qk(next)
__global__ __launch_bounds__(256) void comb_h2_lnqk(const float* __restrict__ Cp,
                                                    const float* __restrict__ zb,
                                                    const float* __restrict__ xb,
                                                    const float* __restrict__ lg,
                                                    const float* __restrict__ lb,
                                                    const float* __restrict__ Wq,
                                                    const float* __restrict__ Wk,
                                                    float* __restrict__ hcur,
                                                    float* __restrict__ outp,
                                                    int slot,
                                                    float* __restrict__ qkb) {
  int n = blockIdx.x, tid = threadIdx.x, c = tid * 4;
  __shared__ float qln[D_], Qp[D_];
  float v[4];
  #pragma unroll
  for (int j = 0; j < 4; ++j) {
    float acc = 0.f;
    #pragma unroll
    for (int ss = 0; ss < KS_; ++ss) acc += Cp[(size_t)ss * (N_ * D_) + (size_t)n * D_ + c + j];
    float z = zb[(size_t)n * D_ + c + j];
    float x = xb[(size_t)n * D_ + c + j];
    v[j] = (1.f - z) * x + z * tanhf(acc);
    hcur[(size_t)n * D_ + c + j] = v[j];
    size_t bi = (slot >= 0) ? (((size_t)n * NB_ + slot) * D_ + c + j)
                            : ((size_t)n * D_ + c + j);
    outp[bi] = v[j];
  }
  if (Wq != nullptr)
    ln_qk_epilogue(n, v, tid, lg, lb, Wq, Wk, qkb, qln, Qp);
}

// ----------------------------------------------------------------
extern "C" void kernel_launch(void* const* d_in, const int* in_sizes, int n_in,
                              void* d_out, int out_size, void* d_ws, size_t ws_size,
                              hipStream_t stream) {
  const float* x    = (const float*)d_in[0];
  const float* mem  = (const float*)d_in[1];
  const int*   mask = (const int*)d_in[2];
  const int*   midx = (const int*)d_in[3];
  const float* We   = (const float*)d_in[5];
  const float* be   = (const float*)d_in[6];
  const float* Wq   = (const float*)d_in[7];
  const float* Wk   = (const float*)d_in[8];
  const float* Wv   = (const float*)d_in[9];
  const float* Wo   = (const float*)d_in[10];
  const float* bo   = (const float*)d_in[11];
  const float* Wfc  = (const float*)d_in[12];
  const float* bfc  = (const float*)d_in[13];
  const float* ln1g = (const float*)d_in[14];
  const float* ln1b = (const float*)d_in[15];
  const float* ln2g = (const float*)d_in[16];
  const float* ln2b = (const float*)d_in[17];
  const float* lnkg = (const float*)d_in[18];
  const float* lnkb = (const float*)d_in[19];
  const float* g1w[7]; for (int j = 0; j < 7; ++j) g1w[j] = (const float*)d_in[20 + j];
  const float* g2w[7]; for (int j = 0; j < 7; ++j) g2w[j] = (const float*)d_in[27 + j];
  float* out = (float*)d_out;
  float* out_li = out + (size_t)N_ * D_;   // layer_inputs region (N, NB, D)

  float* ws   = (float*)d_ws;
  float* pos  = ws; ws += (size_t)T_ * D_;
  float* hcur = ws; ws += N_ * D_;
  float* qkb  = ws; ws += N_ * D_;
  float* tb   = ws; ws += N_ * D_;
  float* ao   = ws; ws += N_ * D_;
  float* rq   = ws; ws += N_ * D_;
  float* zb   = ws; ws += N_ * D_;
  float* h1   = ws; ws += N_ * D_;
  float* hl   = ws; ws += N_ * D_;
  float* fwd  = ws; ws += N_ * D_;
  float* gpart = ws; ws += (size_t)KS_ * N_ * 2048;   // 16 MB
  float* pav   = ws; ws += (size_t)N_ * NCV_ * D_;    // 16 MB
  float* pm    = ws; ws += (size_t)N_ * NCV_ * H_;
  float* ps    = ws; ws += (size_t)N_ * NCV_ * H_;

  const dim3 gp1(16, KS_);     // 1024-col GEMM: 64-col tiles, 256 blocks
  const dim3 gp2(32, KS_);     // 2048-col GEMM: 512 blocks
  const dim3 at_grid(NCV_ / 4, N_);

  pos_kernel<<<T_, 512, 0, stream>>>(pos);

  // embed: h0 = relu(x@We + be); out_li[0]; LN1(layer0)+qk fold
  gemm_part_t<1024, false><<<gp1, 256, 0, stream>>>(x, We, nullptr, nullptr, nullptr, nullptr, gpart);
  comb_embed_lnqk<<<N_, 256, 0, stream>>>(gpart, be, ln1g, ln1b, Wq, Wk, hcur, out_li, qkb);

  for (int i = 0; i < NB_; ++i) {
    size_t oD  = (size_t)i * D_;
    size_t oDD = (size_t)i * D_ * D_;
    size_t oH  = (size_t)i * H_ * DH_ * DH_;

    attn_stream<<<at_grid, 256, 0, stream>>>(mem, pos, mask, midx, qkb,
                                             lnkg + oD, lnkb + oD, i, pav, pm, ps);
    attn_fin<<<N_, 256, 0, stream>>>(pav, pm, ps, Wv + oH, tb);

    gemm_part_t<1024, false><<<gp1, 256, 0, stream>>>(tb, Wo + oDD, nullptr, nullptr, nullptr, nullptr, gpart);
    comb_ew<<<512, 256, 0, stream>>>(gpart, bo + oD, ao, 1);

    // GRU1: x=hcur, y=ao
    gemm_part_t<2048, true><<<gp2, 256, 0, stream>>>(ao, g1w[0] + oDD, g1w[2] + oDD,
                                                     hcur, g1w[1] + oDD, g1w[3] + oDD, gpart);
    comb_rz<<<512, 256, 0, stream>>>(gpart, g1w[6] + oD, hcur, rq, zb);
    gemm_part_t<1024, true><<<gp1, 256, 0, stream>>>(ao, g1w[4] + oDD, nullptr,
                                                     rq, g1w[5] + oDD, nullptr, gpart);
    comb_h_ln<<<N_, 256, 0, stream>>>(gpart, zb, hcur, ln2g + oD, ln2b + oD, h1, hl);

    gemm_part_t<1024, false><<<gp1, 256, 0, stream>>>(hl, Wfc + oDD, nullptr, nullptr, nullptr, nullptr, gpart);
    comb_ew<<<512, 256, 0, stream>>>(gpart, bfc + oD, fwd, 0);

    // GRU2: x=h1, y=fwd
    gemm_part_t<2048, true><<<gp2, 256, 0, stream>>>(fwd, g2w[0] + oDD, g2w[2] + oDD,
                                                     h1, g2w[1] + oDD, g2w[3] + oDD, gpart);
    comb_rz<<<512, 256, 0, stream>>>(gpart, g2w[6] + oD, h1, rq, zb);
    gemm_part_t<1024, true><<<gp1, 256, 0, stream>>>(fwd, g2w[4] + oDD, nullptr,
                                                     rq, g2w[5] + oDD, nullptr, gpart);

    bool last = (i == NB_ - 1);
    float* outp = last ? out : out_li;
    int slot = last ? -1 : (i + 1);
    const float* nWq = last ? nullptr : (Wq + oH + H_ * DH_ * DH_);
    const float* nWk = last ? nullptr : (Wk + oH + H_ * DH_ * DH_);
    const float* nlg = last ? nullptr : (ln1g + oD + D_);
    const float* nlb = last ? nullptr : (ln1b + oD + D_);
    comb_h2_lnqk<<<N_, 256, 0, stream>>>(gpart, zb, h1, nlg, nlb, nWq, nWk,
                                         hcur, outp, slot, qkb);
  }
}